// Round 1
// baseline (2800.991 us; speedup 1.0000x reference)
//
#include <hip/hip_runtime.h>
#include <hip/hip_bf16.h>

// GRU last-hidden: B=64, T=512, I=256, H=512, fp32 in/out.
// Persistent kernel: 64 WGs x 256 thr. WG w owns h-cols [8w,8w+8) for ALL
// batches; weights live in VGPR MFMA B-fragments for the whole kernel.
//
// Round-6 change: DRAIN-FREE SELF-VALIDATING h exchange. R5's chain had ~4
// serial L3 round-trips per step: (1) producer vmcnt(0) store-drain before
// the tag (data-before-flag), (2) tag flight, (3) consumer tag-poll RT,
// (4) h-load RT. Now each published h element is a dword
// (step_tag<<16)|bf16 — per-dword atomicity means tag+payload can never
// tear, so the producer fires data + tag with NO drain (kills RT 1), and
// the consumer SPECULATIVELY issues data+tag loads together and validates
// the embedded tags with a 128-wide umin (merges RT 3+4 on the fast path).
// The wave's own fragment is substituted from LDS (own stores are not
// self-visible without a drain). The separate tag array survives only as
// a cheap spin gate for the miss path; correctness rests entirely on the
// embedded per-dword tags. Overwrite safety: a producer's visible tagged
// h_{t+1} data-depends on its h_t loads (MFMA consumed them), and every
// WG validates all 64 producers before overwriting its buffer parity.

#define NB 64
#define NT 512
#define NI 256
#define NH 512

typedef __attribute__((ext_vector_type(8))) short bf16x8;
typedef __attribute__((ext_vector_type(4))) float f32x4;
typedef __attribute__((ext_vector_type(4))) int i32x4;
typedef __attribute__((ext_vector_type(4))) unsigned int u32x4;

static __device__ __forceinline__ short f2b(float f) {
  unsigned u = __builtin_bit_cast(unsigned, f);
  unsigned r = (u + 0x7fffu + ((u >> 16) & 1u)) >> 16;
  return (short)r;
}
static __device__ __forceinline__ float sigm(float x) {
  return 1.0f / (1.0f + __expf(-x));
}
static __device__ __forceinline__ float tanh_f(float x) {
  return 1.0f - 2.0f / (__expf(2.0f * x) + 1.0f);
}

__global__ __launch_bounds__(256, 1)
void gru_persistent(const float* __restrict__ x,
                    const float* __restrict__ Wih,
                    const float* __restrict__ Whh,
                    const float* __restrict__ bih,
                    const float* __restrict__ bhh,
                    float* __restrict__ out,
                    unsigned char* __restrict__ ws) {
  const int wg   = blockIdx.x;    // 0..63 : owns h-cols [8wg, 8wg+8)
  const int tid  = threadIdx.x;   // 0..255
  const int wave = tid >> 6;      // 0..3  : owns batches [16*wave, 16*wave+16)
  const int lane = tid & 63;
  const int c    = lane & 15;     // tile col / A-row index
  const int q    = lane >> 4;     // quad: k-group (A/B), row-group (C/D)

  // ws layout: [0,8K) init-barrier slots; [8K,9K) tags[4][64] (int);
  // h_ex dword bufs at 16K and 16K+128K ([64 wg][64 b][8 cols] dwords,
  // each dword = (step_tag<<16)|bf16 — 128KB each); xb at 16K+256K.
  int* slots = (int*)ws;
  int* tags  = (int*)(ws + 8192);
  unsigned* hb0 = (unsigned*)(ws + 16384);
  unsigned* hb1 = (unsigned*)(ws + 16384 + 131072);
  unsigned short* xb = (unsigned short*)(ws + 16384 + 262144);

  __shared__ __align__(16) unsigned short trans[4][16][8];  // per-wave bounce

  // ---- prologue: x fp32->bf16, zero h bufs (tag 0 == valid h0), tags ----
  {
    const float4* x4 = (const float4*)x;
    const int total4 = NB * NT * NI / 4;
    const int nthr = NB * 256;
    for (int i = wg * 256 + tid; i < total4; i += nthr) {
      float4 v = x4[i];
      ushort4 o;
      o.x = (unsigned short)f2b(v.x);
      o.y = (unsigned short)f2b(v.y);
      o.z = (unsigned short)f2b(v.z);
      o.w = (unsigned short)f2b(v.w);
      ((ushort4*)xb)[i] = o;
    }
    // hb0 (h0 = 0, tag 0) and hb1 (tag 0 = stale until step-0 publish):
    // contiguous 65536 dwords.
    for (int i = wg * 256 + tid; i < 65536; i += nthr) hb0[i] = 0u;
    if (wg == 0) tags[tid] = 0;       // 256 tags
    ((unsigned*)trans)[tid] = 0u;     // trans = h0 slice = 0 (256 dwords)
  }

  // ---- loop-invariant weight fragments into registers ----
  bf16x8 wh[2][16];  // W_hh, K=512 -> 16 k-steps
  bf16x8 wi[2][8];   // W_ih, K=256 -> 8 k-steps
#pragma unroll
  for (int nt = 0; nt < 2; nt++) {
    int nl = nt * 16 + c;
    bool valid = nl < 24;
    int gate = nl >> 3;
    int jj = nl & 7;
    int grow = valid ? (gate * NH + wg * 8 + jj) : 0;
#pragma unroll
    for (int kk = 0; kk < 16; kk++) {
      const float* p = Whh + (size_t)grow * NH + kk * 32 + q * 8;
      bf16x8 f;
#pragma unroll
      for (int e = 0; e < 8; e++) f[e] = valid ? f2b(p[e]) : (short)0;
      wh[nt][kk] = f;
    }
#pragma unroll
    for (int kk = 0; kk < 8; kk++) {
      const float* p = Wih + (size_t)grow * NI + kk * 32 + q * 8;
      bf16x8 f;
#pragma unroll
      for (int e = 0; e < 8; e++) f[e] = valid ? f2b(p[e]) : (short)0;
      wi[nt][kk] = f;
    }
  }

  const int jcol = wg * 8 + (c & 7);
  const float bri = bih[jcol],          brh = bhh[jcol];
  const float bzi = bih[NH + jcol],     bzh = bhh[NH + jcol];
  const float bni = bih[2 * NH + jcol], bnh = bhh[2 * NH + jcol];

  float hold[4] = {0.f, 0.f, 0.f, 0.f};  // fp32 master state (c<8 lanes)

  // ---- one-time init barrier: xb, h bufs, tag zeros visible device-wide ----
  __syncthreads();
  if (tid == 0)
    __hip_atomic_store(&slots[wg * 32], 1, __ATOMIC_RELEASE,
                       __HIP_MEMORY_SCOPE_AGENT);
  if (wave == 0) {
    while (__hip_atomic_load(&slots[lane * 32], __ATOMIC_RELAXED,
                             __HIP_MEMORY_SCOPE_AGENT) < 1)
      __builtin_amdgcn_s_sleep(1);
  }
  __syncthreads();
  __threadfence();

  const int b0 = wave * 16 + c;       // A-fragment batch row for this lane
  int* mytags = tags + wave * 64;     // this sync plane's 64 tags
  const int* tagp = mytags + lane;    // per-lane poll address (coalesced)
  const int kk_own = wg >> 2;         // fragment holding our own cols
  const bool own = (q == (wg & 3));   // lanes of that fragment that are ours

  // 32 coalesced 16B agent-coherent loads of tagged h dwords.
#define LOAD_ALL()                                                            \
  do {                                                                        \
    const char* hbase_ = (const char*)hcur;                                   \
    _Pragma("unroll") for (int kk2 = 0; kk2 < 16; kk2++) {                    \
      const void* ap_ = hbase_ + (size_t)(((kk2 * 4 + q) * 64 + b0) << 5);    \
      asm volatile("global_load_dwordx4 %0, %1, off sc1"                      \
                   : "=v"(hv[kk2][0]) : "v"(ap_));                            \
      asm volatile("global_load_dwordx4 %0, %1, off offset:16 sc1"            \
                   : "=v"(hv[kk2][1]) : "v"(ap_));                            \
    }                                                                         \
  } while (0)

  // One wait with register deps on every loaded vector (16 operands max
  // per asm -> two blocks; the second vmcnt(0) is free).
#define WAIT_ALL()                                                            \
  do {                                                                        \
    asm volatile("s_waitcnt vmcnt(0)"                                         \
        : "+v"(hv[0][0]), "+v"(hv[0][1]), "+v"(hv[1][0]), "+v"(hv[1][1]),     \
          "+v"(hv[2][0]), "+v"(hv[2][1]), "+v"(hv[3][0]), "+v"(hv[3][1]),     \
          "+v"(hv[4][0]), "+v"(hv[4][1]), "+v"(hv[5][0]), "+v"(hv[5][1]),     \
          "+v"(hv[6][0]), "+v"(hv[6][1]), "+v"(hv[7][0]), "+v"(hv[7][1])      \
        :: "memory");                                                         \
    asm volatile("s_waitcnt vmcnt(0)"                                         \
        : "+v"(hv[8][0]),  "+v"(hv[8][1]),  "+v"(hv[9][0]),  "+v"(hv[9][1]),  \
          "+v"(hv[10][0]), "+v"(hv[10][1]), "+v"(hv[11][0]), "+v"(hv[11][1]), \
          "+v"(hv[12][0]), "+v"(hv[12][1]), "+v"(hv[13][0]), "+v"(hv[13][1]), \
          "+v"(hv[14][0]), "+v"(hv[14][1]), "+v"(hv[15][0]), "+v"(hv[15][1]), \
          "+v"(tv)                                                            \
        :: "memory");                                                         \
  } while (0)

  // Substitute own-WG fragment lanes from LDS (tagged as fresh), then
  // validate all embedded tags via unsigned min >= (t<<16).
#define SUBVAL(mn_)                                                           \
  do {                                                                        \
    _Pragma("unroll") for (int kk2 = 0; kk2 < 16; kk2++) {                    \
      if (kk2 == kk_own) {                                                    \
        hv[kk2][0][0] = own ? (int)td0 : hv[kk2][0][0];                       \
        hv[kk2][0][1] = own ? (int)td1 : hv[kk2][0][1];                       \
        hv[kk2][0][2] = own ? (int)td2 : hv[kk2][0][2];                       \
        hv[kk2][0][3] = own ? (int)td3 : hv[kk2][0][3];                       \
        hv[kk2][1][0] = own ? (int)td4 : hv[kk2][1][0];                       \
        hv[kk2][1][1] = own ? (int)td5 : hv[kk2][1][1];                       \
        hv[kk2][1][2] = own ? (int)td6 : hv[kk2][1][2];                       \
        hv[kk2][1][3] = own ? (int)td7 : hv[kk2][1][3];                       \
      }                                                                       \
    }                                                                         \
    mn_ = 0xffffffffu;                                                        \
    _Pragma("unroll") for (int kk2 = 0; kk2 < 16; kk2++) {                    \
      _Pragma("unroll") for (int h2 = 0; h2 < 2; h2++) {                      \
        _Pragma("unroll") for (int j2 = 0; j2 < 4; j2++) {                    \
          unsigned d_ = (unsigned)hv[kk2][h2][j2];                            \
          mn_ = d_ < mn_ ? d_ : mn_;                                          \
        }                                                                     \
      }                                                                       \
    }                                                                         \
  } while (0)

  for (int t = 0; t < NT; t++) {
    const unsigned* hcur = (t & 1) ? hb1 : hb0;
    unsigned* hnext      = (t & 1) ? hb0 : hb1;

    f32x4 aX0 = {0.f, 0.f, 0.f, 0.f}, aX1 = {0.f, 0.f, 0.f, 0.f};
    f32x4 aH0 = {0.f, 0.f, 0.f, 0.f}, aH1 = {0.f, 0.f, 0.f, 0.f};

    const bf16x8* xr = (const bf16x8*)(xb + ((size_t)b0 * NT + t) * NI);

    // x-projection (cached loads; fills the wall-clock while producers'
    // packets are in flight). Fully before the exchange.
#pragma unroll
    for (int kk = 0; kk < 8; kk++) {
      bf16x8 a = xr[kk * 4 + q];
      aX0 = __builtin_amdgcn_mfma_f32_16x16x32_bf16(a, wi[0][kk], aX0, 0, 0, 0);
      aX1 = __builtin_amdgcn_mfma_f32_16x16x32_bf16(a, wi[1][kk], aX1, 0, 0, 0);
    }

    const unsigned bound = (unsigned)t << 16;

    i32x4 hv[16][2];
    int tv = t;

    // ---- speculative combined attempt: data + tag in one round trip ----
    LOAD_ALL();
    if (t > 0)
      asm volatile("global_load_dword %0, %1, off sc1" : "=v"(tv) : "v"(tagp));

    // own-fragment h_t from LDS (written by our epilogue last step; zeros
    // at t=0), pre-tagged as fresh. Overlaps with global-load flight.
    const unsigned* lp = (const unsigned*)&trans[wave][c][0];
    unsigned lw0 = lp[0], lw1 = lp[1], lw2 = lp[2], lw3 = lp[3];
    unsigned td0 = bound | (lw0 & 0xffffu), td1 = bound | (lw0 >> 16);
    unsigned td2 = bound | (lw1 & 0xffffu), td3 = bound | (lw1 >> 16);
    unsigned td4 = bound | (lw2 & 0xffffu), td5 = bound | (lw2 >> 16);
    unsigned td6 = bound | (lw3 & 0xffffu), td7 = bound | (lw3 >> 16);

    WAIT_ALL();
    unsigned mn;
    SUBVAL(mn);
    bool data_ok = __all((int)(mn >= bound));

    // miss path: cheap tag spin (1 coalesced dword / iter), then reload.
    if (t > 0 && !data_ok) {
      while (true) {
        int v;
        asm volatile("global_load_dword %0, %1, off sc1" : "=v"(v) : "v"(tagp));
        asm volatile("s_waitcnt vmcnt(0)" : "+v"(v)::"memory");
        if (__all(v >= t)) break;
      }
    }
    while (!data_ok) {
      LOAD_ALL();
      WAIT_ALL();
      SUBVAL(mn);
      data_ok = __all((int)(mn >= bound));
    }

    // h-projection: strip tags (v_perm low-half pack) and MFMA.
#pragma unroll
    for (int kk = 0; kk < 16; kk++) {
      unsigned w0 = __builtin_amdgcn_perm((unsigned)hv[kk][0][1],
                                          (unsigned)hv[kk][0][0], 0x05040100u);
      unsigned w1 = __builtin_amdgcn_perm((unsigned)hv[kk][0][3],
                                          (unsigned)hv[kk][0][2], 0x05040100u);
      unsigned w2 = __builtin_amdgcn_perm((unsigned)hv[kk][1][1],
                                          (unsigned)hv[kk][1][0], 0x05040100u);
      unsigned w3 = __builtin_amdgcn_perm((unsigned)hv[kk][1][3],
                                          (unsigned)hv[kk][1][2], 0x05040100u);
      u32x4 pk = {w0, w1, w2, w3};
      bf16x8 a = __builtin_bit_cast(bf16x8, pk);
      aH0 = __builtin_amdgcn_mfma_f32_16x16x32_bf16(a, wh[0][kk], aH0, 0, 0, 0);
      aH1 = __builtin_amdgcn_mfma_f32_16x16x32_bf16(a, wh[1][kk], aH1, 0, 0, 0);
    }

    // epilogue: C/D layout col=lane&15, row=q*4+reg. Lane c<8 owns col wg*8+c.
#pragma unroll
    for (int r = 0; r < 4; r++) {
      float xz = __shfl_xor(aX0[r], 8, 64);
      float hz = __shfl_xor(aH0[r], 8, 64);
      float rr = sigm(aX0[r] + bri + aH0[r] + brh);
      float zz = sigm(xz + bzi + hz + bzh);
      float nn = tanh_f(aX1[r] + bni + rr * (aH1[r] + bnh));
      float hv2 = (1.0f - zz) * nn + zz * hold[r];
      hold[r] = hv2;
      if (c < 8) trans[wave][q * 4 + r][c] = (unsigned short)f2b(hv2);
    }

    if (t < NT - 1) {
      // per-wave LDS transpose -> tagged dword packets, fire-and-forget:
      // NO vmcnt drain before the tag — embedded tags carry correctness.
      asm volatile("s_waitcnt lgkmcnt(0)" ::: "memory");
      if (lane < 16) {
        int b = wave * 16 + lane;
        const unsigned* tp = (const unsigned*)&trans[wave][lane][0];
        unsigned s0 = tp[0], s1 = tp[1], s2 = tp[2], s3 = tp[3];
        unsigned tg = (unsigned)(t + 1) << 16;
        i32x4 lo, hi;
        lo[0] = (int)(tg | (s0 & 0xffffu)); lo[1] = (int)(tg | (s0 >> 16));
        lo[2] = (int)(tg | (s1 & 0xffffu)); lo[3] = (int)(tg | (s1 >> 16));
        hi[0] = (int)(tg | (s2 & 0xffffu)); hi[1] = (int)(tg | (s2 >> 16));
        hi[2] = (int)(tg | (s3 & 0xffffu)); hi[3] = (int)(tg | (s3 >> 16));
        void* dst = (char*)hnext + ((size_t)(wg * 64 + b) << 5);
        asm volatile("global_store_dwordx4 %0, %1, off sc1"
                     :: "v"(dst), "v"(lo) : "memory");
        asm volatile("global_store_dwordx4 %0, %1, off offset:16 sc1"
                     :: "v"(dst), "v"(hi) : "memory");
      }
      // tag is a spin HINT only (monotone); no ordering required.
      if (lane == 0)
        __hip_atomic_store(&mytags[wg], t + 1, __ATOMIC_RELAXED,
                           __HIP_MEMORY_SCOPE_AGENT);
    }
  }

  // final h (fp32 master copy) -> d_out
  if (c < 8) {
#pragma unroll
    for (int r = 0; r < 4; r++) {
      int b = wave * 16 + q * 4 + r;
      out[(size_t)b * NH + wg * 8 + c] = hold[r];
    }
  }
}

extern "C" void kernel_launch(void* const* d_in, const int* in_sizes, int n_in,
                              void* d_out, int out_size, void* d_ws, size_t ws_size,
                              hipStream_t stream) {
  const float* x   = (const float*)d_in[0];
  const float* Wih = (const float*)d_in[1];
  const float* Whh = (const float*)d_in[2];
  const float* bih = (const float*)d_in[3];
  const float* bhh = (const float*)d_in[4];
  float* out = (float*)d_out;
  hipLaunchKernelGGL(gru_persistent, dim3(NB), dim3(256), 0, stream,
                     x, Wih, Whh, bih, bhh, out, (unsigned char*)d_ws);
}

// Round 2
// 1921.232 us; speedup vs baseline: 1.4579x; 1.4579x over previous
//
#include <hip/hip_runtime.h>
#include <hip/hip_bf16.h>

// GRU last-hidden: B=64, T=512, I=256, H=512, fp32 in/out.
// Persistent kernel: 64 WGs x 256 thr. WG w owns h-cols [8w,8w+8) for ALL
// batches; weights live in VGPR MFMA B-fragments for the whole kernel.
//
// Round-7: revert to R5 structure (16B bf16 packets, poll-first consumer
// — R6's 32B tagged packets doubled L3 burst traffic and its speculation
// always missed, +1.2us/step). Remove ONLY the producer store-drain RT via
// a SENTINEL protocol:
//  * at step-t start (after the poll, which already certifies all readers
//    of the slot are done) each wave writes sentinel 0xFFFFFFFF (bf16
//    -NaN pair, unreachable from f2b of h in (-1,1)) over the slot it
//    will publish into — 1 dword/lane, fire-and-forget;
//  * at publish, s_waitcnt vmcnt(0) is FREE (only the ~2000-cycle-old
//    sentinel is outstanding; its ack already returned), then data store
//    and tag store issue back-to-back with NO drain between them;
//  * tag>=need now certifies "sentinel at L3"; per-dword atomicity means
//    consumers see sentinel-or-fresh, validated by a cheap umax tree with
//    a rare reload on the tag-beats-data window. Stale-accept impossible.
// Also: dual-outstanding poll loads halve poll-detect quantization
// (vmcnt(1) always covers the older in-flight poll; both regs stay live
// through the later vmcnt(0) so the dangling load can't clobber).

#define NB 64
#define NT 512
#define NI 256
#define NH 512

#define SENT 0xffffffffu

typedef __attribute__((ext_vector_type(8))) short bf16x8;
typedef __attribute__((ext_vector_type(4))) float f32x4;
typedef __attribute__((ext_vector_type(4))) int i32x4;

static __device__ __forceinline__ short f2b(float f) {
  unsigned u = __builtin_bit_cast(unsigned, f);
  unsigned r = (u + 0x7fffu + ((u >> 16) & 1u)) >> 16;
  return (short)r;
}
static __device__ __forceinline__ float sigm(float x) {
  return 1.0f / (1.0f + __expf(-x));
}
static __device__ __forceinline__ float tanh_f(float x) {
  return 1.0f - 2.0f / (__expf(2.0f * x) + 1.0f);
}

__global__ __launch_bounds__(256, 1)
void gru_persistent(const float* __restrict__ x,
                    const float* __restrict__ Wih,
                    const float* __restrict__ Whh,
                    const float* __restrict__ bih,
                    const float* __restrict__ bhh,
                    float* __restrict__ out,
                    unsigned char* __restrict__ ws) {
  const int wg   = blockIdx.x;    // 0..63 : owns h-cols [8wg, 8wg+8)
  const int tid  = threadIdx.x;   // 0..255
  const int wave = tid >> 6;      // 0..3  : owns batches [16*wave, 16*wave+16)
  const int lane = tid & 63;
  const int c    = lane & 15;     // tile col / A-row index
  const int q    = lane >> 4;     // quad: k-group (A/B), row-group (C/D)

  // ws layout: [0,8K) init-barrier slots; [8K,9K) tags[4][64] (int);
  // h_ex bufs at 16K and 16K+64K ([64 wg][64 b][8 cols] bf16 = 64KB each);
  // xb (x as bf16, [b][t][i]) at 16K+128K.
  int* slots = (int*)ws;
  int* tags  = (int*)(ws + 8192);
  unsigned short* hb0 = (unsigned short*)(ws + 16384);
  unsigned short* hb1 = (unsigned short*)(ws + 16384 + 65536);
  unsigned short* xb  = (unsigned short*)(ws + 16384 + 2 * 65536);

  __shared__ __align__(16) unsigned short trans[4][16][8];  // per-wave bounce

  // ---- prologue: x fp32->bf16, zero h0 and tags ----
  {
    const float4* x4 = (const float4*)x;
    const int total4 = NB * NT * NI / 4;
    const int nthr = NB * 256;
    for (int i = wg * 256 + tid; i < total4; i += nthr) {
      float4 v = x4[i];
      ushort4 o;
      o.x = (unsigned short)f2b(v.x);
      o.y = (unsigned short)f2b(v.y);
      o.z = (unsigned short)f2b(v.z);
      o.w = (unsigned short)f2b(v.w);
      ((ushort4*)xb)[i] = o;
    }
    ((unsigned int*)hb0)[wg * 256 + tid] = 0u;  // h0 = 0 (64KB total)
    if (wg == 0) tags[tid] = 0;                 // 256 tags
  }

  // ---- loop-invariant weight fragments into registers ----
  bf16x8 wh[2][16];  // W_hh, K=512 -> 16 k-steps
  bf16x8 wi[2][8];   // W_ih, K=256 -> 8 k-steps
#pragma unroll
  for (int nt = 0; nt < 2; nt++) {
    int nl = nt * 16 + c;
    bool valid = nl < 24;
    int gate = nl >> 3;
    int jj = nl & 7;
    int grow = valid ? (gate * NH + wg * 8 + jj) : 0;
#pragma unroll
    for (int kk = 0; kk < 16; kk++) {
      const float* p = Whh + (size_t)grow * NH + kk * 32 + q * 8;
      bf16x8 f;
#pragma unroll
      for (int e = 0; e < 8; e++) f[e] = valid ? f2b(p[e]) : (short)0;
      wh[nt][kk] = f;
    }
#pragma unroll
    for (int kk = 0; kk < 8; kk++) {
      const float* p = Wih + (size_t)grow * NI + kk * 32 + q * 8;
      bf16x8 f;
#pragma unroll
      for (int e = 0; e < 8; e++) f[e] = valid ? f2b(p[e]) : (short)0;
      wi[nt][kk] = f;
    }
  }

  const int jcol = wg * 8 + (c & 7);
  const float bri = bih[jcol],          brh = bhh[jcol];
  const float bzi = bih[NH + jcol],     bzh = bhh[NH + jcol];
  const float bni = bih[2 * NH + jcol], bnh = bhh[2 * NH + jcol];

  float hold[4] = {0.f, 0.f, 0.f, 0.f};  // fp32 master state (c<8 lanes)

  // ---- one-time init barrier: xb, h0, tag zeros visible device-wide ----
  __syncthreads();
  if (tid == 0)
    __hip_atomic_store(&slots[wg * 32], 1, __ATOMIC_RELEASE,
                       __HIP_MEMORY_SCOPE_AGENT);
  if (wave == 0) {
    while (__hip_atomic_load(&slots[lane * 32], __ATOMIC_RELAXED,
                             __HIP_MEMORY_SCOPE_AGENT) < 1)
      __builtin_amdgcn_s_sleep(1);
  }
  __syncthreads();
  __threadfence();

  const int b0 = wave * 16 + c;       // A-fragment batch row for this lane
  int* mytags = tags + wave * 64;     // this wave-plane's 64 tags
  const int* tagp = mytags + lane;    // per-lane poll address (coalesced)

  // 16 coalesced 16B agent-coherent loads of the full h fragment set.
#define LOAD_ALL()                                                            \
  do {                                                                        \
    const char* hbase_ = (const char*)hcur;                                   \
    _Pragma("unroll") for (int kk2 = 0; kk2 < 16; kk2++) {                    \
      const void* ap_ = hbase_ + (size_t)(((kk2 * 4 + q) * 64 + b0) << 4);    \
      asm volatile("global_load_dwordx4 %0, %1, off sc1"                      \
                   : "=v"(hv[kk2]) : "v"(ap_));                               \
    }                                                                         \
  } while (0)

  // One wait with register deps on every loaded vector. va/vb kept live
  // so a dangling poll load can never land in a reallocated register.
#define WAIT_ALL()                                                            \
  asm volatile("s_waitcnt vmcnt(0)"                                           \
               : "+v"(hv[0]), "+v"(hv[1]), "+v"(hv[2]), "+v"(hv[3]),          \
                 "+v"(hv[4]), "+v"(hv[5]), "+v"(hv[6]), "+v"(hv[7]),          \
                 "+v"(hv[8]), "+v"(hv[9]), "+v"(hv[10]), "+v"(hv[11]),        \
                 "+v"(hv[12]), "+v"(hv[13]), "+v"(hv[14]), "+v"(hv[15]),      \
                 "+v"(va), "+v"(vb)                                           \
               ::"memory")

  // Max over all 64 loaded dwords; any SENT dword -> retry.
#define UMAX64(mx_)                                                           \
  do {                                                                        \
    mx_ = 0u;                                                                 \
    _Pragma("unroll") for (int kk2 = 0; kk2 < 16; kk2++) {                    \
      _Pragma("unroll") for (int j2 = 0; j2 < 4; j2++) {                      \
        unsigned d_ = (unsigned)hv[kk2][j2];                                  \
        mx_ = d_ > mx_ ? d_ : mx_;                                            \
      }                                                                       \
    }                                                                         \
  } while (0)

  for (int t = 0; t < NT; t++) {
    const unsigned short* hcur = (t & 1) ? hb1 : hb0;
    unsigned short* hnext      = (t & 1) ? hb0 : hb1;

    f32x4 aX0 = {0.f, 0.f, 0.f, 0.f}, aX1 = {0.f, 0.f, 0.f, 0.f};
    f32x4 aH0 = {0.f, 0.f, 0.f, 0.f}, aH1 = {0.f, 0.f, 0.f, 0.f};

    const bf16x8* xr = (const bf16x8*)(xb + ((size_t)b0 * NT + t) * NI);

    // x-projection (cached loads; fills the wall-clock while producers'
    // packets + tags are in flight). Fully before the poll.
#pragma unroll
    for (int kk = 0; kk < 8; kk++) {
      bf16x8 a = xr[kk * 4 + q];
      aX0 = __builtin_amdgcn_mfma_f32_16x16x32_bf16(a, wi[0][kk], aX0, 0, 0, 0);
      aX1 = __builtin_amdgcn_mfma_f32_16x16x32_bf16(a, wi[1][kk], aX1, 0, 0, 0);
    }

    int va = 0, vb = 0;

    // poll for h_t from this wave-plane's 64 producers: two coalesced
    // agent-coherent dword loads in flight -> detect lag ~ RT/2.
    // vmcnt(1) always covers the OLDER of the two loads (in-order
    // retirement), so the checked register is always valid; a stale
    // value is monotonically old -> conservative retry only.
    if (t > 0) {
      const int need = t + 1;
      asm volatile("global_load_dword %0, %1, off sc1" : "=v"(va) : "v"(tagp));
      for (;;) {
        asm volatile("global_load_dword %0, %1, off sc1" : "=v"(vb) : "v"(tagp));
        asm volatile("s_waitcnt vmcnt(1)" : "+v"(va)::"memory");
        if (__all(va >= need)) break;
        asm volatile("global_load_dword %0, %1, off sc1" : "=v"(va) : "v"(tagp));
        asm volatile("s_waitcnt vmcnt(1)" : "+v"(vb)::"memory");
        if (__all(vb >= need)) break;
      }
    }

    // sentinel-prime the slot we will publish into (h_{t+1}'s home, which
    // all consumers of h_{t-1} are provably done with once our poll
    // passed). 1 dword per lane, fire-and-forget; its ack returns during
    // the load+MFMA phase so the publish-side vmcnt(0) is free.
    if (t < NT - 1) {
      unsigned* sp = (unsigned*)hnext + ((wg * 64 + wave * 16) << 2) + lane;
      asm volatile("global_store_dword %0, %1, off sc1"
                   :: "v"(sp), "v"(SENT) : "memory");
    }

    // h fragment burst + validation (retry covers the tag-beats-data
    // window, which is rare since the poll RT exceeds store-flight skew).
    i32x4 hv[16];
    LOAD_ALL();
    WAIT_ALL();
    unsigned mx;
    UMAX64(mx);
    while (!__all((int)(mx != SENT))) {
      LOAD_ALL();
      WAIT_ALL();
      UMAX64(mx);
    }

    // h-projection
#pragma unroll
    for (int kk = 0; kk < 16; kk++) {
      bf16x8 a = __builtin_bit_cast(bf16x8, hv[kk]);
      aH0 = __builtin_amdgcn_mfma_f32_16x16x32_bf16(a, wh[0][kk], aH0, 0, 0, 0);
      aH1 = __builtin_amdgcn_mfma_f32_16x16x32_bf16(a, wh[1][kk], aH1, 0, 0, 0);
    }

    // epilogue: C/D layout col=lane&15, row=q*4+reg. Lane c<8 owns col wg*8+c.
#pragma unroll
    for (int r = 0; r < 4; r++) {
      float xz = __shfl_xor(aX0[r], 8, 64);
      float hz = __shfl_xor(aH0[r], 8, 64);
      float rr = sigm(aX0[r] + bri + aH0[r] + brh);
      float zz = sigm(xz + bzi + hz + bzh);
      float nn = tanh_f(aX1[r] + bni + rr * (aH1[r] + bnh));
      float hv2 = (1.0f - zz) * nn + zz * hold[r];
      hold[r] = hv2;
      if (c < 8) trans[wave][q * 4 + r][c] = (unsigned short)f2b(hv2);
    }

    if (t < NT - 1) {
      // per-wave LDS transpose -> coalesced 16B data stores. The vmcnt(0)
      // here is FREE (drains only the step-start sentinel, already acked)
      // and orders sentinel-before-data at same addresses AND sentinel-
      // before-tag; data and tag then issue back-to-back with NO drain.
      asm volatile("s_waitcnt lgkmcnt(0)" ::: "memory");
      asm volatile("s_waitcnt vmcnt(0)" ::: "memory");
      if (lane < 16) {
        int b = wave * 16 + lane;
        i32x4 pk = *(const i32x4*)&trans[wave][lane][0];
        void* dst = (char*)hnext + ((size_t)(wg * 64 + b) << 4);
        asm volatile("global_store_dwordx4 %0, %1, off sc1"
                     :: "v"(dst), "v"(pk) : "memory");
      }
      // tag publishes immediately (monotone value; certifies sentinel-at-
      // L3 + producer progress; data freshness is sentinel-validated).
      if (lane == 0)
        __hip_atomic_store(&mytags[wg], t + 2, __ATOMIC_RELAXED,
                           __HIP_MEMORY_SCOPE_AGENT);
    }
  }

  // final h (fp32 master copy) -> d_out
  if (c < 8) {
#pragma unroll
    for (int r = 0; r < 4; r++) {
      int b = wave * 16 + q * 4 + r;
      out[(size_t)b * NH + wg * 8 + c] = hold[r];
    }
  }
}

extern "C" void kernel_launch(void* const* d_in, const int* in_sizes, int n_in,
                              void* d_out, int out_size, void* d_ws, size_t ws_size,
                              hipStream_t stream) {
  const float* x   = (const float*)d_in[0];
  const float* Wih = (const float*)d_in[1];
  const float* Whh = (const float*)d_in[2];
  const float* bih = (const float*)d_in[3];
  const float* bhh = (const float*)d_in[4];
  float* out = (float*)d_out;
  hipLaunchKernelGGL(gru_persistent, dim3(NB), dim3(256), 0, stream,
                     x, Wih, Whh, bih, bhh, out, (unsigned char*)d_ws);
}

// Round 3
// 1820.828 us; speedup vs baseline: 1.5383x; 1.0551x over previous
//
#include <hip/hip_runtime.h>
#include <hip/hip_bf16.h>

// GRU last-hidden: B=64, T=512, I=256, H=512, fp32 in/out.
// Persistent kernel: 64 WGs x 256 thr. WG w owns h-cols [8w,8w+8) for ALL
// batches; weights live in VGPR MFMA B-fragments for the whole kernel.
//
// Round-8: POLL-FREE exchange via 4-deep ring + sentinel-validated
// speculative loads. R7 post-mortem: producer drain was never on the
// critical path; the consumer's serialized poll(~1.5RT)+load(1RT) with
// sc1 RT ~2000cy is. Now:
//  * ring of 4 h buffers; at step-t TOP each wave sentinel-primes its
//    slot in buf[(t+2)%4] (holds h_{t-2}, readers certified done by step
//    t-1's validation) — issued at cycle ~0, fire-and-forget;
//  * the pre-publish vmcnt(0) (free: prime acked long before) forces
//    prime-acked-before-data-issued. Induction: consumer validated
//    h_{t+1} ⟹ producer's step-t data landed ⟹ its step-t prime landed
//    earlier ⟹ buf[(t+2)%4] is sentinel-or-fresh whenever sampled at
//    step t+2. Stale-accept impossible; per-dword atomicity, no tearing.
//  * consumer: x-proj, sched_barrier(0), 16 spec loads + one vmcnt(0) +
//    64-wide umax validation. Fast path = ONE load RT, no poll at all.
//    Miss path: dual-outstanding tag spin (tags are pure hints) + reload.
//  * boundary: buf0 = h0 = zeros (passes umax), buf1 = SENT (prologue);
//    buf2/buf3 primed in-loop at steps 0/1.

#define NB 64
#define NT 512
#define NI 256
#define NH 512

#define SENT 0xffffffffu

typedef __attribute__((ext_vector_type(8))) short bf16x8;
typedef __attribute__((ext_vector_type(4))) float f32x4;
typedef __attribute__((ext_vector_type(4))) int i32x4;

static __device__ __forceinline__ short f2b(float f) {
  unsigned u = __builtin_bit_cast(unsigned, f);
  unsigned r = (u + 0x7fffu + ((u >> 16) & 1u)) >> 16;
  return (short)r;
}
static __device__ __forceinline__ float sigm(float x) {
  return 1.0f / (1.0f + __expf(-x));
}
static __device__ __forceinline__ float tanh_f(float x) {
  return 1.0f - 2.0f / (__expf(2.0f * x) + 1.0f);
}

__global__ __launch_bounds__(256, 1)
void gru_persistent(const float* __restrict__ x,
                    const float* __restrict__ Wih,
                    const float* __restrict__ Whh,
                    const float* __restrict__ bih,
                    const float* __restrict__ bhh,
                    float* __restrict__ out,
                    unsigned char* __restrict__ ws) {
  const int wg   = blockIdx.x;    // 0..63 : owns h-cols [8wg, 8wg+8)
  const int tid  = threadIdx.x;   // 0..255
  const int wave = tid >> 6;      // 0..3  : owns batches [16*wave, 16*wave+16)
  const int lane = tid & 63;
  const int c    = lane & 15;     // tile col / A-row index
  const int q    = lane >> 4;     // quad: k-group (A/B), row-group (C/D)

  // ws layout: [0,8K) init-barrier slots; [8K,9K) tags[4][64] (int);
  // ring of 4 h bufs at 16K + 64K*k ([64 wg][64 b][8 cols] bf16 = 64KB
  // each); xb (x as bf16, [b][t][i]) at 16K+256K.
  int* slots = (int*)ws;
  int* tags  = (int*)(ws + 8192);
  unsigned short* hb = (unsigned short*)(ws + 16384);       // ring base
  unsigned short* xb = (unsigned short*)(ws + 16384 + 262144);

  __shared__ __align__(16) unsigned short trans[4][16][8];  // per-wave bounce

  // ---- prologue: x fp32->bf16; buf0 = h0 = 0; buf1 = SENT; tags = 0 ----
  {
    const float4* x4 = (const float4*)x;
    const int total4 = NB * NT * NI / 4;
    const int nthr = NB * 256;
    for (int i = wg * 256 + tid; i < total4; i += nthr) {
      float4 v = x4[i];
      ushort4 o;
      o.x = (unsigned short)f2b(v.x);
      o.y = (unsigned short)f2b(v.y);
      o.z = (unsigned short)f2b(v.z);
      o.w = (unsigned short)f2b(v.w);
      ((ushort4*)xb)[i] = o;
    }
    ((unsigned int*)hb)[wg * 256 + tid] = 0u;           // buf0 = h0 = 0
    ((unsigned int*)hb)[16384 + wg * 256 + tid] = SENT; // buf1 = sentinel
    if (wg == 0) tags[tid] = 0;                         // 256 tags
  }

  // ---- loop-invariant weight fragments into registers ----
  bf16x8 wh[2][16];  // W_hh, K=512 -> 16 k-steps
  bf16x8 wi[2][8];   // W_ih, K=256 -> 8 k-steps
#pragma unroll
  for (int nt = 0; nt < 2; nt++) {
    int nl = nt * 16 + c;
    bool valid = nl < 24;
    int gate = nl >> 3;
    int jj = nl & 7;
    int grow = valid ? (gate * NH + wg * 8 + jj) : 0;
#pragma unroll
    for (int kk = 0; kk < 16; kk++) {
      const float* p = Whh + (size_t)grow * NH + kk * 32 + q * 8;
      bf16x8 f;
#pragma unroll
      for (int e = 0; e < 8; e++) f[e] = valid ? f2b(p[e]) : (short)0;
      wh[nt][kk] = f;
    }
#pragma unroll
    for (int kk = 0; kk < 8; kk++) {
      const float* p = Wih + (size_t)grow * NI + kk * 32 + q * 8;
      bf16x8 f;
#pragma unroll
      for (int e = 0; e < 8; e++) f[e] = valid ? f2b(p[e]) : (short)0;
      wi[nt][kk] = f;
    }
  }

  const int jcol = wg * 8 + (c & 7);
  const float bri = bih[jcol],          brh = bhh[jcol];
  const float bzi = bih[NH + jcol],     bzh = bhh[NH + jcol];
  const float bni = bih[2 * NH + jcol], bnh = bhh[2 * NH + jcol];

  float hold[4] = {0.f, 0.f, 0.f, 0.f};  // fp32 master state (c<8 lanes)

  // ---- one-time init barrier: xb, bufs, tag zeros visible device-wide ----
  __syncthreads();
  if (tid == 0)
    __hip_atomic_store(&slots[wg * 32], 1, __ATOMIC_RELEASE,
                       __HIP_MEMORY_SCOPE_AGENT);
  if (wave == 0) {
    while (__hip_atomic_load(&slots[lane * 32], __ATOMIC_RELAXED,
                             __HIP_MEMORY_SCOPE_AGENT) < 1)
      __builtin_amdgcn_s_sleep(1);
  }
  __syncthreads();
  __threadfence();

  const int b0 = wave * 16 + c;       // A-fragment batch row for this lane
  int* mytags = tags + wave * 64;     // this wave-plane's 64 tags
  const int* tagp = mytags + lane;    // per-lane poll address (coalesced)

  // 16 coalesced 16B agent-coherent loads of the full h fragment set.
#define LOAD_ALL()                                                            \
  do {                                                                        \
    const char* hbase_ = (const char*)hcur;                                   \
    _Pragma("unroll") for (int kk2 = 0; kk2 < 16; kk2++) {                    \
      const void* ap_ = hbase_ + (size_t)(((kk2 * 4 + q) * 64 + b0) << 4);    \
      asm volatile("global_load_dwordx4 %0, %1, off sc1"                      \
                   : "=v"(hv[kk2]) : "v"(ap_));                               \
    }                                                                         \
  } while (0)

  // One wait with register deps on every loaded vector. va/vb kept live
  // so a dangling poll load can never land in a reallocated register.
#define WAIT_ALL()                                                            \
  asm volatile("s_waitcnt vmcnt(0)"                                           \
               : "+v"(hv[0]), "+v"(hv[1]), "+v"(hv[2]), "+v"(hv[3]),          \
                 "+v"(hv[4]), "+v"(hv[5]), "+v"(hv[6]), "+v"(hv[7]),          \
                 "+v"(hv[8]), "+v"(hv[9]), "+v"(hv[10]), "+v"(hv[11]),        \
                 "+v"(hv[12]), "+v"(hv[13]), "+v"(hv[14]), "+v"(hv[15]),      \
                 "+v"(va), "+v"(vb)                                           \
               ::"memory")

  // Max over all 64 loaded dwords; any SENT dword -> stale/in-flight.
#define UMAX64(mx_)                                                           \
  do {                                                                        \
    mx_ = 0u;                                                                 \
    _Pragma("unroll") for (int kk2 = 0; kk2 < 16; kk2++) {                    \
      _Pragma("unroll") for (int j2 = 0; j2 < 4; j2++) {                      \
        unsigned d_ = (unsigned)hv[kk2][j2];                                  \
        mx_ = d_ > mx_ ? d_ : mx_;                                            \
      }                                                                       \
    }                                                                         \
  } while (0)

  for (int t = 0; t < NT; t++) {
    const unsigned short* hcur = hb + ((size_t)(t & 3) << 15);
    unsigned short* hnext      = hb + ((size_t)((t + 1) & 3) << 15);
    unsigned short* hprime     = hb + ((size_t)((t + 2) & 3) << 15);

    // 1) sentinel-prime buf[(t+2)%4] (holds h_{t-2}; its readers were
    // certified done by step t-1's validation). Issued at step TOP so its
    // ack returns long before the pre-publish vmcnt(0) -> that drain is
    // free yet forces prime-acked-before-data-issued (soundness chain).
    if (t < NT - 2) {
      unsigned* sp = (unsigned*)hprime + ((wg * 64 + wave * 16) << 2) + lane;
      asm volatile("global_store_dword %0, %1, off sc1"
                   :: "v"(sp), "v"(SENT) : "memory");
    }

    f32x4 aX0 = {0.f, 0.f, 0.f, 0.f}, aX1 = {0.f, 0.f, 0.f, 0.f};
    f32x4 aH0 = {0.f, 0.f, 0.f, 0.f}, aH1 = {0.f, 0.f, 0.f, 0.f};

    const bf16x8* xr = (const bf16x8*)(xb + ((size_t)b0 * NT + t) * NI);

    // 2) x-projection first: delays the speculative sample ~400cy past
    // the producers' data arrival at L3 -> fast path dominant.
#pragma unroll
    for (int kk = 0; kk < 8; kk++) {
      bf16x8 a = xr[kk * 4 + q];
      aX0 = __builtin_amdgcn_mfma_f32_16x16x32_bf16(a, wi[0][kk], aX0, 0, 0, 0);
      aX1 = __builtin_amdgcn_mfma_f32_16x16x32_bf16(a, wi[1][kk], aX1, 0, 0, 0);
    }
    __builtin_amdgcn_sched_barrier(0);  // pin x-proj above the spec loads

    int va = 0, vb = 0;
    i32x4 hv[16];

    // 3) speculative h loads + single wait + sentinel validation.
    // Fast path: one RT, NO poll. buf is sentinel-or-fresh by induction.
    LOAD_ALL();
    WAIT_ALL();
    unsigned mx;
    UMAX64(mx);

    if (!__all((int)(mx != SENT))) {
      // miss path: cheap dual-outstanding tag spin (tags are pure hints;
      // vmcnt(1) always covers the OLDER in-flight load), then reload.
      if (t > 0) {
        const int need = t + 1;
        asm volatile("global_load_dword %0, %1, off sc1" : "=v"(va) : "v"(tagp));
        for (;;) {
          asm volatile("global_load_dword %0, %1, off sc1" : "=v"(vb) : "v"(tagp));
          asm volatile("s_waitcnt vmcnt(1)" : "+v"(va)::"memory");
          if (__all(va >= need)) break;
          asm volatile("global_load_dword %0, %1, off sc1" : "=v"(va) : "v"(tagp));
          asm volatile("s_waitcnt vmcnt(1)" : "+v"(vb)::"memory");
          if (__all(vb >= need)) break;
        }
      }
      do {
        LOAD_ALL();
        WAIT_ALL();
        UMAX64(mx);
      } while (!__all((int)(mx != SENT)));
    }

    // 4) h-projection
#pragma unroll
    for (int kk = 0; kk < 16; kk++) {
      bf16x8 a = __builtin_bit_cast(bf16x8, hv[kk]);
      aH0 = __builtin_amdgcn_mfma_f32_16x16x32_bf16(a, wh[0][kk], aH0, 0, 0, 0);
      aH1 = __builtin_amdgcn_mfma_f32_16x16x32_bf16(a, wh[1][kk], aH1, 0, 0, 0);
    }

    // 5) epilogue: C/D layout col=lane&15, row=q*4+reg. Lane c<8 owns
    // col wg*8+c.
#pragma unroll
    for (int r = 0; r < 4; r++) {
      float xz = __shfl_xor(aX0[r], 8, 64);
      float hz = __shfl_xor(aH0[r], 8, 64);
      float rr = sigm(aX0[r] + bri + aH0[r] + brh);
      float zz = sigm(xz + bzi + hz + bzh);
      float nn = tanh_f(aX1[r] + bni + rr * (aH1[r] + bnh));
      float hv2 = (1.0f - zz) * nn + zz * hold[r];
      hold[r] = hv2;
      if (c < 8) trans[wave][q * 4 + r][c] = (unsigned short)f2b(hv2);
    }

    if (t < NT - 1) {
      // 6) publish. vmcnt(0) is free (prime acked ~a full step ago; spec
      // loads long returned) but REQUIRED: it orders prime-acked before
      // data-issued, which the speculation soundness induction uses.
      asm volatile("s_waitcnt lgkmcnt(0)" ::: "memory");
      asm volatile("s_waitcnt vmcnt(0)" ::: "memory");
      if (lane < 16) {
        int b = wave * 16 + lane;
        i32x4 pk = *(const i32x4*)&trans[wave][lane][0];
        void* dst = (char*)hnext + ((size_t)(wg * 64 + b) << 4);
        asm volatile("global_store_dwordx4 %0, %1, off sc1"
                     :: "v"(dst), "v"(pk) : "memory");
      }
      // tag = hint for the miss-path spin only (monotone).
      if (lane == 0)
        __hip_atomic_store(&mytags[wg], t + 2, __ATOMIC_RELAXED,
                           __HIP_MEMORY_SCOPE_AGENT);
    }
  }

  // final h (fp32 master copy) -> d_out
  if (c < 8) {
#pragma unroll
    for (int r = 0; r < 4; r++) {
      int b = wave * 16 + q * 4 + r;
      out[(size_t)b * NH + wg * 8 + c] = hold[r];
    }
  }
}

extern "C" void kernel_launch(void* const* d_in, const int* in_sizes, int n_in,
                              void* d_out, int out_size, void* d_ws, size_t ws_size,
                              hipStream_t stream) {
  const float* x   = (const float*)d_in[0];
  const float* Wih = (const float*)d_in[1];
  const float* Whh = (const float*)d_in[2];
  const float* bih = (const float*)d_in[3];
  const float* bhh = (const float*)d_in[4];
  float* out = (float*)d_out;
  hipLaunchKernelGGL(gru_persistent, dim3(NB), dim3(256), 0, stream,
                     x, Wih, Whh, bih, bhh, out, (unsigned char*)d_ws);
}